// Round 18
// baseline (169.119 us; speedup 1.0000x reference)
//
#include <hip/hip_runtime.h>
#include <hip/hip_bf16.h>

// Problem constants (B=1)
#define T_DIM 4096
#define E_DIM 1024
#define H_DIM 16
#define HD_DIM 64
#define LOG2E_F 1.4426950408889634f
#define QSCALE_F (0.125f * LOG2E_F)   // SCALE * log2(e), folded into Qp

typedef __bf16 bf16_t;
typedef __bf16 bf16x8 __attribute__((ext_vector_type(8)));
typedef __bf16 bf16x4 __attribute__((ext_vector_type(4)));
typedef float  f32x4  __attribute__((ext_vector_type(4)));
typedef float  f32x16 __attribute__((ext_vector_type(16)));

// ---- helpers ----
__device__ inline void stage8(bf16_t* dst, const float* src) {
  const f32x4* s4 = (const f32x4*)src;
  f32x4 a = s4[0], b = s4[1];
  bf16x8 o;
  o[0] = (bf16_t)a[0]; o[1] = (bf16_t)a[1]; o[2] = (bf16_t)a[2]; o[3] = (bf16_t)a[3];
  o[4] = (bf16_t)b[0]; o[5] = (bf16_t)b[1]; o[6] = (bf16_t)b[2]; o[7] = (bf16_t)b[3];
  *(bf16x8*)dst = o;
}
__device__ inline void stage8(bf16_t* dst, const bf16_t* src) {
  *(bf16x8*)dst = *(const bf16x8*)src;
}

__device__ inline void gld_lds16(const bf16_t* g, bf16_t* l) {
  __builtin_amdgcn_global_load_lds(
      (const __attribute__((address_space(1))) unsigned int*)g,
      (__attribute__((address_space(3))) unsigned int*)l, 16, 0, 0);
}

__device__ inline float fexp2(float x) {  // raw v_exp_f32 (exp2)
  float r;
  asm("v_exp_f32 %0, %1" : "=v"(r) : "v"(x));
  return r;
}

// raw barrier (no implicit vmcnt(0) drain) + compiler memory fence
__device__ inline void block_sync() {
  asm volatile("" ::: "memory");
  __builtin_amdgcn_s_barrier();
  asm volatile("" ::: "memory");
}

// ---- fp32 -> bf16 conversion for all 7 inputs (one launch) ----
__global__ __launch_bounds__(256) void cvt_all(
    const float* __restrict__ q, const float* __restrict__ k, const float* __restrict__ v,
    const float* __restrict__ Wq, const float* __restrict__ Wk,
    const float* __restrict__ Wv, const float* __restrict__ Wo,
    bf16_t* qb, bf16_t* kb, bf16_t* vb,
    bf16_t* Wqb, bf16_t* Wkb, bf16_t* Wvb, bf16_t* Wob) {
  for (int u = blockIdx.x * 256 + threadIdx.x; u < 2097152; u += gridDim.x * 256) {
    const float* s; bf16_t* d; int i;
    if (u < 1572864) {
      int seg = u >> 19, off = u & 524287;
      s = seg == 0 ? q : (seg == 1 ? k : v);
      d = seg == 0 ? qb : (seg == 1 ? kb : vb);
      i = off;
    } else {
      int w = u - 1572864;
      int seg = w >> 17, off = w & 131071;
      s = seg == 0 ? Wq : seg == 1 ? Wk : seg == 2 ? Wv : Wo;
      d = seg == 0 ? Wqb : seg == 1 ? Wkb : seg == 2 ? Wvb : Wob;
      i = off;
    }
    stage8(d + (size_t)i * 8, s + (size_t)i * 8);
  }
}

// ---- bf16 GEMM tile body (m97 structure): C = (A[M][1024] x B[N][1024]^T)*cs
template <int MF, int NF, typename TC>
__device__ __forceinline__ void gemm_body(const bf16_t* __restrict__ A,
                                          const bf16_t* __restrict__ B,
                                          TC* __restrict__ C,
                                          int ldC, int bm, int bn, float cs) {
  constexpr int BM = 32 * MF, BN = 32 * NF;
  __shared__ alignas(16) bf16_t As[BM][64];
  __shared__ alignas(16) bf16_t Bs[BN][64];
  const int tid  = threadIdx.x;
  const int lane = tid & 63, w = tid >> 6;
  const int g = lane >> 4, l15 = lane & 15;
  const int wr = w >> 1, wc = w & 1;

  f32x4 acc[MF][NF] = {};

  for (int kt = 0; kt < 1024; kt += 64) {
    if (kt) __syncthreads();
#pragma unroll
    for (int p = 0; p < MF; ++p) {
      int s = p * 256 + tid;
      int row = s >> 3, c = s & 7;
      int cg = c ^ (row & 7);
      gld_lds16(&A[(size_t)(bm + row) * 1024 + kt + cg * 8], &As[0][0] + s * 8);
    }
#pragma unroll
    for (int p = 0; p < NF; ++p) {
      int s = p * 256 + tid;
      int row = s >> 3, c = s & 7;
      int cg = c ^ (row & 7);
      gld_lds16(&B[(size_t)(bn + row) * 1024 + kt + cg * 8], &Bs[0][0] + s * 8);
    }
    asm volatile("s_waitcnt vmcnt(0)" ::: "memory");
    __syncthreads();

#pragma unroll
    for (int hh = 0; hh < 2; ++hh) {
      bf16x8 af[MF], bfr[NF];
#pragma unroll
      for (int m = 0; m < MF; ++m) {
        int row = wr * (16 * MF) + m * 16 + l15;
        af[m] = *(const bf16x8*)(&As[0][0] + row * 64 + (((hh * 4 + g) ^ (row & 7)) * 8));
      }
#pragma unroll
      for (int n = 0; n < NF; ++n) {
        int row = wc * (16 * NF) + n * 16 + l15;
        bfr[n] = *(const bf16x8*)(&Bs[0][0] + row * 64 + (((hh * 4 + g) ^ (row & 7)) * 8));
      }
#pragma unroll
      for (int m = 0; m < MF; ++m)
#pragma unroll
        for (int n = 0; n < NF; ++n)
          acc[m][n] = __builtin_amdgcn_mfma_f32_16x16x32_bf16(af[m], bfr[n], acc[m][n], 0, 0, 0);
    }
  }

#pragma unroll
  for (int m = 0; m < MF; ++m)
#pragma unroll
    for (int n = 0; n < NF; ++n)
#pragma unroll
      for (int r = 0; r < 4; ++r) {
        int row = bm + wr * (16 * MF) + m * 16 + g * 4 + r;
        int col = bn + wc * (16 * NF) + n * 16 + l15;
        C[(size_t)row * ldC + col] = (TC)(acc[m][n][r] * cs);
      }
}

// ---- fused Q/K/V projections: one launch, 768 blocks (3 blocks/CU) ----
__global__ __launch_bounds__(256) void proj_qkv(
    const bf16_t* __restrict__ qb, const bf16_t* __restrict__ kb,
    const bf16_t* __restrict__ vb,
    const bf16_t* __restrict__ Wqb, const bf16_t* __restrict__ Wkb,
    const bf16_t* __restrict__ Wvb,
    bf16_t* Qp, bf16_t* Kp, bf16_t* Vt) {
  const int bid = blockIdx.x;
  const int which = bid >> 8, t = bid & 255;
  const bf16_t *A, *B; bf16_t* C; int ldC, bm, bn; float cs;
  if (which == 0) {
    A = qb;  B = Wqb; C = Qp; ldC = 1024;
    bm = (t >> 3) * 128; bn = (t & 7) * 128; cs = QSCALE_F;
  } else if (which == 1) {
    A = kb;  B = Wkb; C = Kp; ldC = 1024;
    bm = (t >> 3) * 128; bn = (t & 7) * 128; cs = 1.0f;
  } else {
    A = Wvb; B = vb;  C = Vt; ldC = 4096;
    bm = (t >> 5) * 128; bn = (t & 31) * 128; cs = 1.0f;
  }
  gemm_body<4, 4, bf16_t>(A, B, C, ldC, bm, bn, cs);
}

// ---- final GEMM: out = Oa @ Wo^T, 64x128 tiles (grid 8x64, 2 blocks/CU) ----
__global__ __launch_bounds__(256) void gemm_fin(const bf16_t* __restrict__ A,
                                                const bf16_t* __restrict__ B,
                                                float* __restrict__ C) {
  gemm_body<2, 4, float>(A, B, C, 1024, blockIdx.y * 64, blockIdx.x * 128, 1.0f);
}

// ---- fallback GEMM (fp32 staging, used only if ws too small) ----
template <typename TA, typename TB, typename TC>
__global__ __launch_bounds__(256) void gemm_bt(const TA* __restrict__ A,
                                               const TB* __restrict__ B,
                                               TC* __restrict__ C,
                                               int M, int N, int K, float cscale) {
  __shared__ alignas(16) bf16_t As[128][40];
  __shared__ alignas(16) bf16_t Bs[128][40];
  const int tid  = threadIdx.x;
  const int lane = tid & 63, w = tid >> 6;
  const int g = lane >> 4, l15 = lane & 15;
  const int wr = w >> 1, wc = w & 1;
  const int bm = blockIdx.y * 128, bn = blockIdx.x * 128;

  f32x4 acc[4][4] = {};

  for (int kt = 0; kt < K; kt += 32) {
    __syncthreads();
#pragma unroll
    for (int i = 0; i < 2; ++i) {
      int vv  = tid + i * 256;
      int row = vv >> 2, c8 = (vv & 3) * 8;
      stage8(&As[row][c8], &A[(size_t)(bm + row) * K + kt + c8]);
      stage8(&Bs[row][c8], &B[(size_t)(bn + row) * K + kt + c8]);
    }
    __syncthreads();

    bf16x8 af[4], bfr[4];
#pragma unroll
    for (int m = 0; m < 4; ++m)
      af[m] = *(const bf16x8*)&As[wr * 64 + m * 16 + l15][g * 8];
#pragma unroll
    for (int n = 0; n < 4; ++n)
      bfr[n] = *(const bf16x8*)&Bs[wc * 64 + n * 16 + l15][g * 8];
#pragma unroll
    for (int m = 0; m < 4; ++m)
#pragma unroll
      for (int n = 0; n < 4; ++n)
        acc[m][n] = __builtin_amdgcn_mfma_f32_16x16x32_bf16(af[m], bfr[n], acc[m][n], 0, 0, 0);
  }

#pragma unroll
  for (int m = 0; m < 4; ++m)
#pragma unroll
    for (int n = 0; n < 4; ++n)
#pragma unroll
      for (int r = 0; r < 4; ++r) {
        int row = bm + wr * 64 + m * 16 + g * 4 + r;
        int col = bn + wc * 64 + n * 16 + l15;
        C[(size_t)row * N + col] = (TC)(acc[m][n][r] * cscale);
      }
}

// ---- Flash attention, causal, online softmax (log2 domain, pre-scaled Q) ----
// 32x32x16 MFMA restructure (round-17 diagnosis: LDS-issue-bound).
// 4 waves (256 thr), wave owns 32 q-rows (QBLK=128), KVBLK=64.
// Swapped QK^T: S^T = mfma(K, Q); D layout col=lane&31 (q), row=(reg&3)+
// 8*(reg>>2)+4*(lane>>5) (k_local). Lane pair (l, l^32) shares a q-row.
// Per wave-phase LDS: 8 b128 K + 8 b128 V + 4 b128 P-read + 8 b64 P-write
// for 32 rows -- 0.6x round-17 traffic. Pipeline identical to round 15
// (K[2]/V[3], single barrier, delayed PV, 1-ahead issue, vmcnt(0)).
// l via ones-trick MFMA on the P fragments (4 extra MFMAs, no VALU tree).
__global__ __launch_bounds__(256) void attn_fwd(const bf16_t* __restrict__ Qp,
                                                const bf16_t* __restrict__ Kp,
                                                const bf16_t* __restrict__ Vt,
                                                bf16_t* __restrict__ Oattn) {
  const int bid = blockIdx.x;          // 0..511
  const int h   = bid & 15;            // (bid+256)&15 == h: CU pair same head
  const int idx = bid >> 4;            // 0..31
  const int qi  = idx < 16 ? 31 - idx : idx - 16;  // pair (31-i, i) per CU
  const int tid = threadIdx.x, lane = tid & 63, w = tid >> 6;
  const int ql = lane & 31, hl = lane >> 5;
  const int qrow = qi * 128 + w * 32;  // wave w owns 32 q-rows

  __shared__ alignas(16) bf16_t Ks[2][64][64];   // 16 KB, chunk-XOR swizzled
  __shared__ alignas(16) bf16_t Vs[3][64][64];   // 24 KB, chunk-XOR swizzled
  __shared__ alignas(16) bf16_t Plds[4][32][64]; // 16 KB, [wave][q][k] swz

  // Q fragments: B-operand of mfma(K,Q): lane holds Q[q=qrow+ql][d=ds*16+8hl+j]
  bf16x8 qf[4];
  {
    const bf16_t* qp = &Qp[(size_t)(qrow + ql) * E_DIM + h * 64 + 8 * hl];
#pragma unroll
    for (int ds = 0; ds < 4; ++ds) qf[ds] = *(const bf16x8*)(qp + ds * 16);
  }

  bf16x8 ones;
#pragma unroll
  for (int i = 0; i < 8; ++i) ones[i] = (bf16_t)1.0f;

  // staging: 256 threads x 2 chunks x 16B per K and per V tile (64x64 bf16)
  const int row0 = tid >> 3, c0 = tid & 7;
  const int cgo = (c0 ^ (row0 & 7)) * 8;           // source-side swizzle
  const bf16_t* srcK0 = Kp + (size_t)row0 * E_DIM + h * 64 + cgo;
  const bf16_t* srcK1 = srcK0 + (size_t)32 * E_DIM;       // (row+32)&7 == row&7
  const bf16_t* srcV0 = Vt + (size_t)(h * 64 + row0) * T_DIM + cgo;
  const bf16_t* srcV1 = srcV0 + (size_t)32 * T_DIM;
  bf16_t* KsAll = &Ks[0][0][0];
  bf16_t* VsAll = &Vs[0][0][0];
  const size_t KADV = (size_t)64 * E_DIM;
  const int nt = 2 * qi + 2;

  auto issue = [&](int t) {
    bf16_t* kd = KsAll + (t & 1) * 4096;
    bf16_t* vd = VsAll + (t % 3) * 4096;
    gld_lds16(srcK0 + (size_t)t * KADV, kd + tid * 8);
    gld_lds16(srcK1 + (size_t)t * KADV, kd + (256 + tid) * 8);
    gld_lds16(srcV0 + (size_t)t * 64,   vd + tid * 8);
    gld_lds16(srcV1 + (size_t)t * 64,   vd + (256 + tid) * 8);
  };

  f32x16 acc0 = {}, acc1 = {};   // O^T m-tiles: d = m*32 + rowpat, q = ql
  f32x16 acc_l = {};             // ones-trick: acc_l[i] == l[q] for all i
  float m_s = -1e30f;            // row-uniform running max (pair l, l^32)

  const char* Pw = (const char*)&Plds[w][0][0];
  const int x7 = ql & 7;

  auto pv = [&](int t) {
    const char* Vb = (const char*)(VsAll + (t % 3) * 4096);
    bf16x8 pf[4];
#pragma unroll
    for (int ks = 0; ks < 4; ++ks)
      pf[ks] = *(const bf16x8*)(Pw + ql * 128 + (((2 * ks + hl) ^ x7) << 4));
#pragma unroll
    for (int ks = 0; ks < 4; ++ks) {
      bf16x8 v0 = *(const bf16x8*)(Vb + ql * 128        + (((2 * ks + hl) ^ x7) << 4));
      bf16x8 v1 = *(const bf16x8*)(Vb + (32 + ql) * 128 + (((2 * ks + hl) ^ x7) << 4));
      acc0 = __builtin_amdgcn_mfma_f32_32x32x16_bf16(v0, pf[ks], acc0, 0, 0, 0);
      acc1 = __builtin_amdgcn_mfma_f32_32x32x16_bf16(v1, pf[ks], acc1, 0, 0, 0);
      acc_l = __builtin_amdgcn_mfma_f32_32x32x16_bf16(ones, pf[ks], acc_l, 0, 0, 0);
    }
  };

  issue(0);

  for (int j = 0; j < nt; ++j) {
    asm volatile("s_waitcnt vmcnt(0)" ::: "memory");
    block_sync();                 // all waves' K_j,V_j resident; phase j-1 done
    if (j + 1 < nt) issue(j + 1);

    __builtin_amdgcn_s_setprio(1);
    if (j > 0) pv(j - 1);         // PV_{j-1}, one phase late (before rescale!)

    // S^T = K Q'^T from Ks[j&1]: s_m reg i is
    // (k = j*64 + m*32 + (i&3) + 8*(i>>2) + 4*hl, q = qrow + ql)
    const char* Kb = (const char*)(KsAll + (j & 1) * 4096);
    f32x16 s0 = {}, s1 = {};
#pragma unroll
    for (int ds = 0; ds < 4; ++ds) {
      bf16x8 k0 = *(const bf16x8*)(Kb + ql * 128        + (((2 * ds + hl) ^ x7) << 4));
      bf16x8 k1 = *(const bf16x8*)(Kb + (32 + ql) * 128 + (((2 * ds + hl) ^ x7) << 4));
      s0 = __builtin_amdgcn_mfma_f32_32x32x16_bf16(k0, qf[ds], s0, 0, 0, 0);
      s1 = __builtin_amdgcn_mfma_f32_32x32x16_bf16(k1, qf[ds], s1, 0, 0, 0);
    }
    __builtin_amdgcn_s_setprio(0);

    // causal mask: k > q on any tile overlapping/above this wave's rows
    const int kb = j * 64;
    if (kb + 63 > qrow) {
#pragma unroll
      for (int i = 0; i < 16; ++i) {
        int krow = kb + (i & 3) + 8 * (i >> 2) + 4 * hl;
        if (krow > qrow + ql)      s0[i] = -1e30f;
        if (krow + 32 > qrow + ql) s1[i] = -1e30f;
      }
    }

    // online softmax; pmax over 32 regs (tree), row = pair (l, l^32)
    float pmax;
    {
      float t0 = fmaxf(fmaxf(s0[0], s0[1]),  fmaxf(s0[2], s0[3]));
      float t1 = fmaxf(fmaxf(s0[4], s0[5]),  fmaxf(s0[6], s0[7]));
      float t2 = fmaxf(fmaxf(s0[8], s0[9]),  fmaxf(s0[10], s0[11]));
      float t3 = fmaxf(fmaxf(s0[12], s0[13]), fmaxf(s0[14], s0[15]));
      float t4 = fmaxf(fmaxf(s1[0], s1[1]),  fmaxf(s1[2], s1[3]));
      float t5 = fmaxf(fmaxf(s1[4], s1[5]),  fmaxf(s1[6], s1[7]));
      float t6 = fmaxf(fmaxf(s1[8], s1[9]),  fmaxf(s1[10], s1[11]));
      float t7 = fmaxf(fmaxf(s1[12], s1[13]), fmaxf(s1[14], s1[15]));
      pmax = fmaxf(fmaxf(fmaxf(t0, t1), fmaxf(t2, t3)),
                   fmaxf(fmaxf(t4, t5), fmaxf(t6, t7)));
    }

    if (!__all(pmax <= m_s + 11.0f)) {
      float rm = fmaxf(pmax, __shfl_xor(pmax, 32));  // row-uniform max
      float mn = fmaxf(m_s, rm);
      float sc = fexp2(m_s - mn);
      m_s = mn;
#pragma unroll
      for (int i = 0; i < 16; ++i) {
        acc0[i] *= sc; acc1[i] *= sc; acc_l[i] *= sc;
      }
    }

#pragma unroll
    for (int i = 0; i < 16; ++i) {
      s0[i] = fexp2(s0[i] - m_s);
      s1[i] = fexp2(s1[i] - m_s);
    }

    // P -> LDS [q][k] swizzled: quad rq has k = m*32 + 8*rq + 4*hl + (0..3)
#pragma unroll
    for (int rq = 0; rq < 4; ++rq) {
      bf16x4 p0, p1;
#pragma unroll
      for (int r = 0; r < 4; ++r) {
        p0[r] = (bf16_t)s0[rq * 4 + r];
        p1[r] = (bf16_t)s1[rq * 4 + r];
      }
      *(bf16x4*)((char*)Pw + ql * 128 + ((rq ^ x7) << 4)       + 8 * hl) = p0;
      *(bf16x4*)((char*)Pw + ql * 128 + (((4 + rq) ^ x7) << 4) + 8 * hl) = p1;
    }
  }

  // epilogue: PV for the last tile; l straight from acc_l
  pv(nt - 1);

  const float inv = 1.0f / acc_l[0];
#pragma unroll
  for (int rq = 0; rq < 4; ++rq) {
    bf16x4 o0, o1;
#pragma unroll
    for (int r = 0; r < 4; ++r) {
      o0[r] = (bf16_t)(acc0[rq * 4 + r] * inv);
      o1[r] = (bf16_t)(acc1[rq * 4 + r] * inv);
    }
    bf16_t* orow = &Oattn[(size_t)(qrow + ql) * E_DIM + h * 64];
    *(bf16x4*)(orow + 8 * rq + 4 * hl)      = o0;
    *(bf16x4*)(orow + 32 + 8 * rq + 4 * hl) = o1;
  }
}

extern "C" void kernel_launch(void* const* d_in, const int* in_sizes, int n_in,
                              void* d_out, int out_size, void* d_ws, size_t ws_size,
                              hipStream_t stream) {
  const float* q  = (const float*)d_in[0];
  const float* k  = (const float*)d_in[1];
  const float* v  = (const float*)d_in[2];
  const float* Wq = (const float*)d_in[3];
  const float* Wk = (const float*)d_in[4];
  const float* Wv = (const float*)d_in[5];
  const float* Wo = (const float*)d_in[6];
  float* out = (float*)d_out;

  const size_t TE = (size_t)T_DIM * E_DIM;   // 4M elems
  const size_t EE = (size_t)E_DIM * E_DIM;   // 1M elems
  dim3 blk(256);

  if (ws_size >= (size_t)56 * 1024 * 1024) {
    bf16_t* qb  = (bf16_t*)d_ws;          // reused as Oa after projections
    bf16_t* kb  = qb + TE;
    bf16_t* vb  = kb + TE;
    bf16_t* Wqb = vb + TE;
    bf16_t* Wkb = Wqb + EE;
    bf16_t* Wvb = Wkb + EE;
    bf16_t* Wob = Wvb + EE;
    bf16_t* Qp  = Wob + EE;
    bf16_t* Kp  = Qp + TE;
    bf16_t* Vt  = Kp + TE;                // [E][T]
    bf16_t* Oa  = qb;                     // alias

    cvt_all<<<2048, blk, 0, stream>>>(q, k, v, Wq, Wk, Wv, Wo,
                                      qb, kb, vb, Wqb, Wkb, Wvb, Wob);
    proj_qkv<<<dim3(768), blk, 0, stream>>>(qb, kb, vb, Wqb, Wkb, Wvb, Qp, Kp, Vt);
    attn_fwd<<<dim3(512), blk, 0, stream>>>(Qp, Kp, Vt, Oa);
    gemm_fin<<<dim3(8, 64), blk, 0, stream>>>(Oa, Wob, out);
  } else {
    bf16_t* Qp = (bf16_t*)d_ws;
    bf16_t* Kp = Qp + TE;
    bf16_t* Vt = Kp + TE;
    bf16_t* Oa = Vt + TE;
    gemm_bt<float, float, bf16_t><<<dim3(8, 32), blk, 0, stream>>>(q, Wq, Qp, T_DIM, E_DIM, E_DIM, QSCALE_F);
    gemm_bt<float, float, bf16_t><<<dim3(8, 32), blk, 0, stream>>>(k, Wk, Kp, T_DIM, E_DIM, E_DIM, 1.0f);
    gemm_bt<float, float, bf16_t><<<dim3(32, 8), blk, 0, stream>>>(Wv, v, Vt, E_DIM, T_DIM, E_DIM, 1.0f);
    attn_fwd<<<dim3(512), blk, 0, stream>>>(Qp, Kp, Vt, Oa);
    gemm_bt<bf16_t, float, float><<<dim3(8, 32), blk, 0, stream>>>(Oa, Wo, out, T_DIM, E_DIM, E_DIM, 1.0f);
  }
}

// Round 19
// 125.783 us; speedup vs baseline: 1.3445x; 1.3445x over previous
//
#include <hip/hip_runtime.h>
#include <hip/hip_bf16.h>

// Problem constants (B=1)
#define T_DIM 4096
#define E_DIM 1024
#define H_DIM 16
#define HD_DIM 64
#define LOG2E_F 1.4426950408889634f
#define QSCALE_F (0.125f * LOG2E_F)   // SCALE * log2(e), folded into Qp

typedef __bf16 bf16_t;
typedef __bf16 bf16x8 __attribute__((ext_vector_type(8)));
typedef __bf16 bf16x4 __attribute__((ext_vector_type(4)));
typedef float  f32x4  __attribute__((ext_vector_type(4)));

// ---- helpers ----
__device__ inline void stage8(bf16_t* dst, const float* src) {
  const f32x4* s4 = (const f32x4*)src;
  f32x4 a = s4[0], b = s4[1];
  bf16x8 o;
  o[0] = (bf16_t)a[0]; o[1] = (bf16_t)a[1]; o[2] = (bf16_t)a[2]; o[3] = (bf16_t)a[3];
  o[4] = (bf16_t)b[0]; o[5] = (bf16_t)b[1]; o[6] = (bf16_t)b[2]; o[7] = (bf16_t)b[3];
  *(bf16x8*)dst = o;
}
__device__ inline void stage8(bf16_t* dst, const bf16_t* src) {
  *(bf16x8*)dst = *(const bf16x8*)src;
}

__device__ inline void gld_lds16(const bf16_t* g, bf16_t* l) {
  __builtin_amdgcn_global_load_lds(
      (const __attribute__((address_space(1))) unsigned int*)g,
      (__attribute__((address_space(3))) unsigned int*)l, 16, 0, 0);
}

__device__ inline float fexp2(float x) {  // raw v_exp_f32 (exp2)
  float r;
  asm("v_exp_f32 %0, %1" : "=v"(r) : "v"(x));
  return r;
}

// raw barrier (no implicit vmcnt(0) drain) + compiler memory fence
__device__ inline void block_sync() {
  asm volatile("" ::: "memory");
  __builtin_amdgcn_s_barrier();
  asm volatile("" ::: "memory");
}

// ---- fp32 -> bf16 conversion for all 7 inputs (one launch) ----
__global__ __launch_bounds__(256) void cvt_all(
    const float* __restrict__ q, const float* __restrict__ k, const float* __restrict__ v,
    const float* __restrict__ Wq, const float* __restrict__ Wk,
    const float* __restrict__ Wv, const float* __restrict__ Wo,
    bf16_t* qb, bf16_t* kb, bf16_t* vb,
    bf16_t* Wqb, bf16_t* Wkb, bf16_t* Wvb, bf16_t* Wob) {
  for (int u = blockIdx.x * 256 + threadIdx.x; u < 2097152; u += gridDim.x * 256) {
    const float* s; bf16_t* d; int i;
    if (u < 1572864) {
      int seg = u >> 19, off = u & 524287;
      s = seg == 0 ? q : (seg == 1 ? k : v);
      d = seg == 0 ? qb : (seg == 1 ? kb : vb);
      i = off;
    } else {
      int w = u - 1572864;
      int seg = w >> 17, off = w & 131071;
      s = seg == 0 ? Wq : seg == 1 ? Wk : seg == 2 ? Wv : Wo;
      d = seg == 0 ? Wqb : seg == 1 ? Wkb : seg == 2 ? Wvb : Wob;
      i = off;
    }
    stage8(d + (size_t)i * 8, s + (size_t)i * 8);
  }
}

// ---- bf16 GEMM tile body (m97 structure): C = (A[M][1024] x B[N][1024]^T)*cs
template <int MF, int NF, typename TC>
__device__ __forceinline__ void gemm_body(const bf16_t* __restrict__ A,
                                          const bf16_t* __restrict__ B,
                                          TC* __restrict__ C,
                                          int ldC, int bm, int bn, float cs) {
  constexpr int BM = 32 * MF, BN = 32 * NF;
  __shared__ alignas(16) bf16_t As[BM][64];
  __shared__ alignas(16) bf16_t Bs[BN][64];
  const int tid  = threadIdx.x;
  const int lane = tid & 63, w = tid >> 6;
  const int g = lane >> 4, l15 = lane & 15;
  const int wr = w >> 1, wc = w & 1;

  f32x4 acc[MF][NF] = {};

  for (int kt = 0; kt < 1024; kt += 64) {
    if (kt) __syncthreads();
#pragma unroll
    for (int p = 0; p < MF; ++p) {
      int s = p * 256 + tid;
      int row = s >> 3, c = s & 7;
      int cg = c ^ (row & 7);
      gld_lds16(&A[(size_t)(bm + row) * 1024 + kt + cg * 8], &As[0][0] + s * 8);
    }
#pragma unroll
    for (int p = 0; p < NF; ++p) {
      int s = p * 256 + tid;
      int row = s >> 3, c = s & 7;
      int cg = c ^ (row & 7);
      gld_lds16(&B[(size_t)(bn + row) * 1024 + kt + cg * 8], &Bs[0][0] + s * 8);
    }
    asm volatile("s_waitcnt vmcnt(0)" ::: "memory");
    __syncthreads();

#pragma unroll
    for (int hh = 0; hh < 2; ++hh) {
      bf16x8 af[MF], bfr[NF];
#pragma unroll
      for (int m = 0; m < MF; ++m) {
        int row = wr * (16 * MF) + m * 16 + l15;
        af[m] = *(const bf16x8*)(&As[0][0] + row * 64 + (((hh * 4 + g) ^ (row & 7)) * 8));
      }
#pragma unroll
      for (int n = 0; n < NF; ++n) {
        int row = wc * (16 * NF) + n * 16 + l15;
        bfr[n] = *(const bf16x8*)(&Bs[0][0] + row * 64 + (((hh * 4 + g) ^ (row & 7)) * 8));
      }
#pragma unroll
      for (int m = 0; m < MF; ++m)
#pragma unroll
        for (int n = 0; n < NF; ++n)
          acc[m][n] = __builtin_amdgcn_mfma_f32_16x16x32_bf16(af[m], bfr[n], acc[m][n], 0, 0, 0);
    }
  }

#pragma unroll
  for (int m = 0; m < MF; ++m)
#pragma unroll
    for (int n = 0; n < NF; ++n)
#pragma unroll
      for (int r = 0; r < 4; ++r) {
        int row = bm + wr * (16 * MF) + m * 16 + g * 4 + r;
        int col = bn + wc * (16 * NF) + n * 16 + l15;
        C[(size_t)row * ldC + col] = (TC)(acc[m][n][r] * cs);
      }
}

// ---- fused Q/K/V projections: one launch, 768 blocks (3 blocks/CU) ----
__global__ __launch_bounds__(256) void proj_qkv(
    const bf16_t* __restrict__ qb, const bf16_t* __restrict__ kb,
    const bf16_t* __restrict__ vb,
    const bf16_t* __restrict__ Wqb, const bf16_t* __restrict__ Wkb,
    const bf16_t* __restrict__ Wvb,
    bf16_t* Qp, bf16_t* Kp, bf16_t* Vt) {
  const int bid = blockIdx.x;
  const int which = bid >> 8, t = bid & 255;
  const bf16_t *A, *B; bf16_t* C; int ldC, bm, bn; float cs;
  if (which == 0) {
    A = qb;  B = Wqb; C = Qp; ldC = 1024;
    bm = (t >> 3) * 128; bn = (t & 7) * 128; cs = QSCALE_F;
  } else if (which == 1) {
    A = kb;  B = Wkb; C = Kp; ldC = 1024;
    bm = (t >> 3) * 128; bn = (t & 7) * 128; cs = 1.0f;
  } else {
    A = Wvb; B = vb;  C = Vt; ldC = 4096;
    bm = (t >> 5) * 128; bn = (t & 31) * 128; cs = 1.0f;
  }
  gemm_body<4, 4, bf16_t>(A, B, C, ldC, bm, bn, cs);
}

// ---- final GEMM: out = Oa @ Wo^T, 64x128 tiles (grid 8x64, 2 blocks/CU) ----
__global__ __launch_bounds__(256) void gemm_fin(const bf16_t* __restrict__ A,
                                                const bf16_t* __restrict__ B,
                                                float* __restrict__ C) {
  gemm_body<2, 4, float>(A, B, C, 1024, blockIdx.y * 64, blockIdx.x * 128, 1.0f);
}

// ---- fallback GEMM (fp32 staging, used only if ws too small) ----
template <typename TA, typename TB, typename TC>
__global__ __launch_bounds__(256) void gemm_bt(const TA* __restrict__ A,
                                               const TB* __restrict__ B,
                                               TC* __restrict__ C,
                                               int M, int N, int K, float cscale) {
  __shared__ alignas(16) bf16_t As[128][40];
  __shared__ alignas(16) bf16_t Bs[128][40];
  const int tid  = threadIdx.x;
  const int lane = tid & 63, w = tid >> 6;
  const int g = lane >> 4, l15 = lane & 15;
  const int wr = w >> 1, wc = w & 1;
  const int bm = blockIdx.y * 128, bn = blockIdx.x * 128;

  f32x4 acc[4][4] = {};

  for (int kt = 0; kt < K; kt += 32) {
    __syncthreads();
#pragma unroll
    for (int i = 0; i < 2; ++i) {
      int vv  = tid + i * 256;
      int row = vv >> 2, c8 = (vv & 3) * 8;
      stage8(&As[row][c8], &A[(size_t)(bm + row) * K + kt + c8]);
      stage8(&Bs[row][c8], &B[(size_t)(bn + row) * K + kt + c8]);
    }
    __syncthreads();

    bf16x8 af[4], bfr[4];
#pragma unroll
    for (int m = 0; m < 4; ++m)
      af[m] = *(const bf16x8*)&As[wr * 64 + m * 16 + l15][g * 8];
#pragma unroll
    for (int n = 0; n < 4; ++n)
      bfr[n] = *(const bf16x8*)&Bs[wc * 64 + n * 16 + l15][g * 8];
#pragma unroll
    for (int m = 0; m < 4; ++m)
#pragma unroll
      for (int n = 0; n < 4; ++n)
        acc[m][n] = __builtin_amdgcn_mfma_f32_16x16x32_bf16(af[m], bfr[n], acc[m][n], 0, 0, 0);
  }

#pragma unroll
  for (int m = 0; m < 4; ++m)
#pragma unroll
    for (int n = 0; n < 4; ++n)
#pragma unroll
      for (int r = 0; r < 4; ++r) {
        int row = bm + wr * 64 + m * 16 + g * 4 + r;
        int col = bn + wc * 64 + n * 16 + l15;
        C[(size_t)row * N + col] = (TC)(acc[m][n][r] * cscale);
      }
}

// ---- Flash attention, causal, online softmax (log2 domain, pre-scaled Q) ----
// ROUND-17 structure verbatim (best known: 8 waves/512thr, QBLK=128, KVBLK=64,
// single barrier/phase, delayed PV, K double-/V triple-buffer, 1-ahead issue,
// vmcnt(0); l via ones-trick MFMA; pmax via v_max3 nests).
// Round-19 addition: fully-masked waves (w<=3) skip QK/softmax/P on the
// diagonal phase and skip their epilogue pv (their P is identically zero).
// (Rounds 16/18 lessons: deeper prefetch and 32x32 fragments both regress.)
__global__ __launch_bounds__(512) void attn_fwd(const bf16_t* __restrict__ Qp,
                                                const bf16_t* __restrict__ Kp,
                                                const bf16_t* __restrict__ Vt,
                                                bf16_t* __restrict__ Oattn) {
  const int bid = blockIdx.x;          // 0..511
  const int h   = bid & 15;            // (bid+256)&15 == h: CU pair same head
  const int idx = bid >> 4;            // 0..31
  const int qi  = idx < 16 ? 31 - idx : idx - 16;  // pair (31-i, i) per CU
  const int tid = threadIdx.x, lane = tid & 63, w = tid >> 6;
  const int g = lane >> 4, l15 = lane & 15;
  const int qrow = qi * 128 + w * 16;  // wave w owns 16 q-rows

  __shared__ alignas(16) bf16_t Ks[2][64][64];   // 16 KB, swizzled
  __shared__ alignas(16) bf16_t Vs[3][64][64];   // 24 KB, swizzled
  __shared__ alignas(16) bf16_t Plds[8][16][72]; // 18 KB, [q][k], 144B stride

  bf16x8 qf[2];
  {
    const bf16_t* qp = &Qp[(size_t)(qrow + l15) * E_DIM + h * 64 + g * 8];
    qf[0] = *(const bf16x8*)qp;
    qf[1] = *(const bf16x8*)(qp + 32);
  }

  bf16x8 ones;
#pragma unroll
  for (int i = 0; i < 8; ++i) ones[i] = (bf16_t)1.0f;

  // staging: 512 threads x 16B = one 64x64 bf16 tile per (K,V) issue
  const int row0 = tid >> 3, c0 = tid & 7;
  const int cgo = (c0 ^ (row0 & 7)) * 8;           // source-side swizzle
  const bf16_t* srcK = Kp + (size_t)row0 * E_DIM + h * 64 + cgo;
  const bf16_t* srcV = Vt + (size_t)(h * 64 + row0) * T_DIM + cgo;
  bf16_t* KsAll = &Ks[0][0][0];
  bf16_t* VsAll = &Vs[0][0][0];
  const size_t KADV = (size_t)64 * E_DIM;
  const int nt = 2 * qi + 2;

  auto issue = [&](int t) {
    gld_lds16(srcK + (size_t)t * KADV, KsAll + (t & 1) * 4096 + tid * 8);
    gld_lds16(srcV + (size_t)t * 64,   VsAll + (t % 3) * 4096 + tid * 8);
  };

  f32x4 acc[4] = {};          // acc[c][r]: O^T[d = c*16 + g*4 + r][q = l15]
  f32x4 acc_l = {};           // ones-trick row sums: acc_l[r] == l[q], all r
  float m_s = -1e30f;         // row-uniform running max

  auto pv = [&](int t) {
    const char* Vb = (const char*)(VsAll + (t % 3) * 4096);
    bf16x8 pf0 = *(const bf16x8*)&Plds[w][l15][g * 8];        // k = g*8..+7
    bf16x8 pf1 = *(const bf16x8*)&Plds[w][l15][32 + g * 8];   // k = 32+g*8..
#pragma unroll
    for (int c = 0; c < 4; ++c) {
      const int vr = c * 16 + l15;
      const char* rp = Vb + vr * 128;
      const int sw = (vr & 7) << 4;
      bf16x8 v0 = *(const bf16x8*)(rp + ((g * 16) ^ sw));
      bf16x8 v1 = *(const bf16x8*)(rp + ((64 + g * 16) ^ sw));
      acc[c] = __builtin_amdgcn_mfma_f32_16x16x32_bf16(v0, pf0, acc[c], 0, 0, 0);
      acc[c] = __builtin_amdgcn_mfma_f32_16x16x32_bf16(v1, pf1, acc[c], 0, 0, 0);
    }
    // l[q] += sum_k P[k][q] on the MFMA pipe (same pf fragments)
    acc_l = __builtin_amdgcn_mfma_f32_16x16x32_bf16(ones, pf0, acc_l, 0, 0, 0);
    acc_l = __builtin_amdgcn_mfma_f32_16x16x32_bf16(ones, pf1, acc_l, 0, 0, 0);
  };

  issue(0);

  for (int j = 0; j < nt; ++j) {
    asm volatile("s_waitcnt vmcnt(0)" ::: "memory");
    block_sync();                 // all waves' K_j,V_j resident; phase j-1 done
    if (j + 1 < nt) issue(j + 1);

    const int kb = j * 64;
    const bool active = (kb <= qrow + 15);  // wave has any unmasked k

    __builtin_amdgcn_s_setprio(1);
    if (j > 0) pv(j - 1);         // PV_{j-1}, one phase late (before rescale!)

    if (active) {
      // S^T = K (Q*SCALE*log2e)^T from Ks[j&1]: s[j16][r] is
      // (k = j*64 + 16*j16 + 4*g + r, q = qrow + l15)
      const char* Kb = (const char*)(KsAll + (j & 1) * 4096);
      f32x4 s[4] = {};
#pragma unroll
      for (int j16 = 0; j16 < 4; ++j16) {
        const int r0 = j16 * 16 + l15;
        const char* rp = Kb + r0 * 128;
        const int sw = (r0 & 7) << 4;
        bf16x8 k0 = *(const bf16x8*)(rp + ((g * 16) ^ sw));
        bf16x8 k1 = *(const bf16x8*)(rp + ((64 + g * 16) ^ sw));
        s[j16] = __builtin_amdgcn_mfma_f32_16x16x32_bf16(k0, qf[0], s[j16], 0, 0, 0);
        s[j16] = __builtin_amdgcn_mfma_f32_16x16x32_bf16(k1, qf[1], s[j16], 0, 0, 0);
      }
      __builtin_amdgcn_s_setprio(0);

      // causal mask: k > q, on any tile overlapping this wave's rows
      if (kb + 63 > qrow) {
#pragma unroll
        for (int j16 = 0; j16 < 4; ++j16)
#pragma unroll
          for (int r = 0; r < 4; ++r)
            if (kb + j16 * 16 + g * 4 + r > qrow + l15) s[j16][r] = -1e30f;
      }

      // online softmax; pmax via nested max-triples (v_max3, 7 ops for 16)
      float t0 = fmaxf(fmaxf(s[0][0], s[0][1]), s[0][2]);
      float t1 = fmaxf(fmaxf(s[0][3], s[1][0]), s[1][1]);
      float t2 = fmaxf(fmaxf(s[1][2], s[1][3]), s[2][0]);
      float t3 = fmaxf(fmaxf(s[2][1], s[2][2]), s[2][3]);
      float t4 = fmaxf(fmaxf(s[3][0], s[3][1]), s[3][2]);
      float pmax = fmaxf(fmaxf(fmaxf(t0, t1), t2),
                         fmaxf(fmaxf(t3, t4), s[3][3]));

      if (!__all(pmax <= m_s + 11.0f)) {
        float rm = fmaxf(pmax, __shfl_xor(pmax, 16));
        rm = fmaxf(rm, __shfl_xor(rm, 32));     // row-uniform max
        float mn = fmaxf(m_s, rm);
        float sc = fexp2(m_s - mn);
        m_s = mn;
#pragma unroll
        for (int r = 0; r < 4; ++r) acc_l[r] *= sc;
#pragma unroll
        for (int c = 0; c < 4; ++c)
#pragma unroll
          for (int r = 0; r < 4; ++r) acc[c][r] *= sc;
      }

#pragma unroll
      for (int j16 = 0; j16 < 4; ++j16)
#pragma unroll
        for (int r = 0; r < 4; ++r)
          s[j16][r] = fexp2(s[j16][r] - m_s);

      // P -> LDS [q][k]: per j16 the 4 r-values are k-consecutive -> b64
#pragma unroll
      for (int j16 = 0; j16 < 4; ++j16) {
        bf16x4 pk;
        pk[0] = (bf16_t)s[j16][0]; pk[1] = (bf16_t)s[j16][1];
        pk[2] = (bf16_t)s[j16][2]; pk[3] = (bf16_t)s[j16][3];
        *(bf16x4*)&Plds[w][l15][j16 * 16 + g * 4] = pk;
      }
    } else {
      __builtin_amdgcn_s_setprio(0);
    }
  }

  // epilogue: PV for the last tile (skip if this wave was fully masked there
  // -- its P slice would be all-zero), l straight from acc_l
  if ((nt - 1) * 64 <= qrow + 15) pv(nt - 1);

  const float inv = 1.0f / acc_l[0];
#pragma unroll
  for (int c = 0; c < 4; ++c) {
    bf16x4 o;
#pragma unroll
    for (int r = 0; r < 4; ++r) o[r] = (bf16_t)(acc[c][r] * inv);
    *(bf16x4*)&Oattn[(size_t)(qrow + l15) * E_DIM + h * 64 + c * 16 + g * 4] = o;
  }
}

extern "C" void kernel_launch(void* const* d_in, const int* in_sizes, int n_in,
                              void* d_out, int out_size, void* d_ws, size_t ws_size,
                              hipStream_t stream) {
  const float* q  = (const float*)d_in[0];
  const float* k  = (const float*)d_in[1];
  const float* v  = (const float*)d_in[2];
  const float* Wq = (const float*)d_in[3];
  const float* Wk = (const float*)d_in[4];
  const float* Wv = (const float*)d_in[5];
  const float* Wo = (const float*)d_in[6];
  float* out = (float*)d_out;

  const size_t TE = (size_t)T_DIM * E_DIM;   // 4M elems
  const size_t EE = (size_t)E_DIM * E_DIM;   // 1M elems
  dim3 blk(256);

  if (ws_size >= (size_t)56 * 1024 * 1024) {
    bf16_t* qb  = (bf16_t*)d_ws;          // reused as Oa after projections
    bf16_t* kb  = qb + TE;
    bf16_t* vb  = kb + TE;
    bf16_t* Wqb = vb + TE;
    bf16_t* Wkb = Wqb + EE;
    bf16_t* Wvb = Wkb + EE;
    bf16_t* Wob = Wvb + EE;
    bf16_t* Qp  = Wob + EE;
    bf16_t* Kp  = Qp + TE;
    bf16_t* Vt  = Kp + TE;                // [E][T]
    bf16_t* Oa  = qb;                     // alias

    cvt_all<<<2048, blk, 0, stream>>>(q, k, v, Wq, Wk, Wv, Wo,
                                      qb, kb, vb, Wqb, Wkb, Wvb, Wob);
    proj_qkv<<<dim3(768), blk, 0, stream>>>(qb, kb, vb, Wqb, Wkb, Wvb, Qp, Kp, Vt);
    attn_fwd<<<dim3(512), dim3(512), 0, stream>>>(Qp, Kp, Vt, Oa);
    gemm_fin<<<dim3(8, 64), blk, 0, stream>>>(Oa, Wob, out);
  } else {
    bf16_t* Qp = (bf16_t*)d_ws;
    bf16_t* Kp = Qp + TE;
    bf16_t* Vt = Kp + TE;
    bf16_t* Oa = Vt + TE;
    gemm_bt<float, float, bf16_t><<<dim3(8, 32), blk, 0, stream>>>(q, Wq, Qp, T_DIM, E_DIM, E_DIM, QSCALE_F);
    gemm_bt<float, float, bf16_t><<<dim3(8, 32), blk, 0, stream>>>(k, Wk, Kp, T_DIM, E_DIM, E_DIM, 1.0f);
    gemm_bt<float, float, bf16_t><<<dim3(32, 8), blk, 0, stream>>>(Wv, v, Vt, E_DIM, T_DIM, E_DIM, 1.0f);
    attn_fwd<<<dim3(512), dim3(512), 0, stream>>>(Qp, Kp, Vt, Oa);
    gemm_bt<bf16_t, float, float><<<dim3(8, 32), blk, 0, stream>>>(Oa, Wo, out, T_DIM, E_DIM, E_DIM, 1.0f);
  }
}

// Round 20
// 123.981 us; speedup vs baseline: 1.3641x; 1.0145x over previous
//
#include <hip/hip_runtime.h>
#include <hip/hip_bf16.h>

// Problem constants (B=1)
#define T_DIM 4096
#define E_DIM 1024
#define H_DIM 16
#define HD_DIM 64
#define LOG2E_F 1.4426950408889634f
#define QSCALE_F (0.125f * LOG2E_F)   // SCALE * log2(e), folded into Qp

typedef __bf16 bf16_t;
typedef __bf16 bf16x8 __attribute__((ext_vector_type(8)));
typedef __bf16 bf16x4 __attribute__((ext_vector_type(4)));
typedef float  f32x4  __attribute__((ext_vector_type(4)));

// ---- helpers ----
__device__ inline void stage8(bf16_t* dst, const float* src) {
  const f32x4* s4 = (const f32x4*)src;
  f32x4 a = s4[0], b = s4[1];
  bf16x8 o;
  o[0] = (bf16_t)a[0]; o[1] = (bf16_t)a[1]; o[2] = (bf16_t)a[2]; o[3] = (bf16_t)a[3];
  o[4] = (bf16_t)b[0]; o[5] = (bf16_t)b[1]; o[6] = (bf16_t)b[2]; o[7] = (bf16_t)b[3];
  *(bf16x8*)dst = o;
}
__device__ inline void stage8(bf16_t* dst, const bf16_t* src) {
  *(bf16x8*)dst = *(const bf16x8*)src;
}

__device__ inline void gld_lds16(const bf16_t* g, bf16_t* l) {
  __builtin_amdgcn_global_load_lds(
      (const __attribute__((address_space(1))) unsigned int*)g,
      (__attribute__((address_space(3))) unsigned int*)l, 16, 0, 0);
}

__device__ inline float fexp2(float x) {  // raw v_exp_f32 (exp2)
  float r;
  asm("v_exp_f32 %0, %1" : "=v"(r) : "v"(x));
  return r;
}

// raw barrier (no implicit vmcnt(0) drain) + compiler memory fence
__device__ inline void block_sync() {
  asm volatile("" ::: "memory");
  __builtin_amdgcn_s_barrier();
  asm volatile("" ::: "memory");
}

// ---- fp32 -> bf16 conversion for all 7 inputs (one launch) ----
__global__ __launch_bounds__(256) void cvt_all(
    const float* __restrict__ q, const float* __restrict__ k, const float* __restrict__ v,
    const float* __restrict__ Wq, const float* __restrict__ Wk,
    const float* __restrict__ Wv, const float* __restrict__ Wo,
    bf16_t* qb, bf16_t* kb, bf16_t* vb,
    bf16_t* Wqb, bf16_t* Wkb, bf16_t* Wvb, bf16_t* Wob) {
  for (int u = blockIdx.x * 256 + threadIdx.x; u < 2097152; u += gridDim.x * 256) {
    const float* s; bf16_t* d; int i;
    if (u < 1572864) {
      int seg = u >> 19, off = u & 524287;
      s = seg == 0 ? q : (seg == 1 ? k : v);
      d = seg == 0 ? qb : (seg == 1 ? kb : vb);
      i = off;
    } else {
      int w = u - 1572864;
      int seg = w >> 17, off = w & 131071;
      s = seg == 0 ? Wq : seg == 1 ? Wk : seg == 2 ? Wv : Wo;
      d = seg == 0 ? Wqb : seg == 1 ? Wkb : seg == 2 ? Wvb : Wob;
      i = off;
    }
    stage8(d + (size_t)i * 8, s + (size_t)i * 8);
  }
}

// ---- bf16 GEMM tile body (m97 structure): C = (A[M][1024] x B[N][1024]^T)*cs
template <int MF, int NF, typename TC>
__device__ __forceinline__ void gemm_body(const bf16_t* __restrict__ A,
                                          const bf16_t* __restrict__ B,
                                          TC* __restrict__ C,
                                          int ldC, int bm, int bn, float cs) {
  constexpr int BM = 32 * MF, BN = 32 * NF;
  __shared__ alignas(16) bf16_t As[BM][64];
  __shared__ alignas(16) bf16_t Bs[BN][64];
  const int tid  = threadIdx.x;
  const int lane = tid & 63, w = tid >> 6;
  const int g = lane >> 4, l15 = lane & 15;
  const int wr = w >> 1, wc = w & 1;

  f32x4 acc[MF][NF] = {};

  for (int kt = 0; kt < 1024; kt += 64) {
    if (kt) __syncthreads();
#pragma unroll
    for (int p = 0; p < MF; ++p) {
      int s = p * 256 + tid;
      int row = s >> 3, c = s & 7;
      int cg = c ^ (row & 7);
      gld_lds16(&A[(size_t)(bm + row) * 1024 + kt + cg * 8], &As[0][0] + s * 8);
    }
#pragma unroll
    for (int p = 0; p < NF; ++p) {
      int s = p * 256 + tid;
      int row = s >> 3, c = s & 7;
      int cg = c ^ (row & 7);
      gld_lds16(&B[(size_t)(bn + row) * 1024 + kt + cg * 8], &Bs[0][0] + s * 8);
    }
    asm volatile("s_waitcnt vmcnt(0)" ::: "memory");
    __syncthreads();

#pragma unroll
    for (int hh = 0; hh < 2; ++hh) {
      bf16x8 af[MF], bfr[NF];
#pragma unroll
      for (int m = 0; m < MF; ++m) {
        int row = wr * (16 * MF) + m * 16 + l15;
        af[m] = *(const bf16x8*)(&As[0][0] + row * 64 + (((hh * 4 + g) ^ (row & 7)) * 8));
      }
#pragma unroll
      for (int n = 0; n < NF; ++n) {
        int row = wc * (16 * NF) + n * 16 + l15;
        bfr[n] = *(const bf16x8*)(&Bs[0][0] + row * 64 + (((hh * 4 + g) ^ (row & 7)) * 8));
      }
#pragma unroll
      for (int m = 0; m < MF; ++m)
#pragma unroll
        for (int n = 0; n < NF; ++n)
          acc[m][n] = __builtin_amdgcn_mfma_f32_16x16x32_bf16(af[m], bfr[n], acc[m][n], 0, 0, 0);
    }
  }

#pragma unroll
  for (int m = 0; m < MF; ++m)
#pragma unroll
    for (int n = 0; n < NF; ++n)
#pragma unroll
      for (int r = 0; r < 4; ++r) {
        int row = bm + wr * (16 * MF) + m * 16 + g * 4 + r;
        int col = bn + wc * (16 * NF) + n * 16 + l15;
        C[(size_t)row * ldC + col] = (TC)(acc[m][n][r] * cs);
      }
}

// ---- fused Q/K/V projections: one launch, 768 blocks (3 blocks/CU) ----
__global__ __launch_bounds__(256) void proj_qkv(
    const bf16_t* __restrict__ qb, const bf16_t* __restrict__ kb,
    const bf16_t* __restrict__ vb,
    const bf16_t* __restrict__ Wqb, const bf16_t* __restrict__ Wkb,
    const bf16_t* __restrict__ Wvb,
    bf16_t* Qp, bf16_t* Kp, bf16_t* Vt) {
  const int bid = blockIdx.x;
  const int which = bid >> 8, t = bid & 255;
  const bf16_t *A, *B; bf16_t* C; int ldC, bm, bn; float cs;
  if (which == 0) {
    A = qb;  B = Wqb; C = Qp; ldC = 1024;
    bm = (t >> 3) * 128; bn = (t & 7) * 128; cs = QSCALE_F;
  } else if (which == 1) {
    A = kb;  B = Wkb; C = Kp; ldC = 1024;
    bm = (t >> 3) * 128; bn = (t & 7) * 128; cs = 1.0f;
  } else {
    A = Wvb; B = vb;  C = Vt; ldC = 4096;
    bm = (t >> 5) * 128; bn = (t & 31) * 128; cs = 1.0f;
  }
  gemm_body<4, 4, bf16_t>(A, B, C, ldC, bm, bn, cs);
}

// ---- final GEMM: out = Oa @ Wo^T, 64x128 tiles (grid 8x64, 2 blocks/CU) ----
__global__ __launch_bounds__(256) void gemm_fin(const bf16_t* __restrict__ A,
                                                const bf16_t* __restrict__ B,
                                                float* __restrict__ C) {
  gemm_body<2, 4, float>(A, B, C, 1024, blockIdx.y * 64, blockIdx.x * 128, 1.0f);
}

// ---- fallback GEMM (fp32 staging, used only if ws too small) ----
template <typename TA, typename TB, typename TC>
__global__ __launch_bounds__(256) void gemm_bt(const TA* __restrict__ A,
                                               const TB* __restrict__ B,
                                               TC* __restrict__ C,
                                               int M, int N, int K, float cscale) {
  __shared__ alignas(16) bf16_t As[128][40];
  __shared__ alignas(16) bf16_t Bs[128][40];
  const int tid  = threadIdx.x;
  const int lane = tid & 63, w = tid >> 6;
  const int g = lane >> 4, l15 = lane & 15;
  const int wr = w >> 1, wc = w & 1;
  const int bm = blockIdx.y * 128, bn = blockIdx.x * 128;

  f32x4 acc[4][4] = {};

  for (int kt = 0; kt < K; kt += 32) {
    __syncthreads();
#pragma unroll
    for (int i = 0; i < 2; ++i) {
      int vv  = tid + i * 256;
      int row = vv >> 2, c8 = (vv & 3) * 8;
      stage8(&As[row][c8], &A[(size_t)(bm + row) * K + kt + c8]);
      stage8(&Bs[row][c8], &B[(size_t)(bn + row) * K + kt + c8]);
    }
    __syncthreads();

    bf16x8 af[4], bfr[4];
#pragma unroll
    for (int m = 0; m < 4; ++m)
      af[m] = *(const bf16x8*)&As[wr * 64 + m * 16 + l15][g * 8];
#pragma unroll
    for (int n = 0; n < 4; ++n)
      bfr[n] = *(const bf16x8*)&Bs[wc * 64 + n * 16 + l15][g * 8];
#pragma unroll
    for (int m = 0; m < 4; ++m)
#pragma unroll
      for (int n = 0; n < 4; ++n)
        acc[m][n] = __builtin_amdgcn_mfma_f32_16x16x32_bf16(af[m], bfr[n], acc[m][n], 0, 0, 0);
  }

#pragma unroll
  for (int m = 0; m < 4; ++m)
#pragma unroll
    for (int n = 0; n < 4; ++n)
#pragma unroll
      for (int r = 0; r < 4; ++r) {
        int row = bm + wr * 64 + m * 16 + g * 4 + r;
        int col = bn + wc * 64 + n * 16 + l15;
        C[(size_t)row * N + col] = (TC)(acc[m][n][r] * cscale);
      }
}

// ---- Flash attention, causal, online softmax (log2 domain, pre-scaled Q) ----
// ROUND-17 configuration (session best): 8 waves/512thr, QBLK=128, KVBLK=64,
// single barrier/phase, delayed PV, K double-/V triple-buffer, 1-ahead issue,
// vmcnt(0); l via ones-trick MFMA; pmax via v_max3 nests.
// Verified-negative variants (do NOT reapply): 2-deep prefetch (r16),
// 32x32 fragments (r18), KVBLK=32 (r12), 2 row-groups/wave (r14),
// diagonal-phase wave skip (r19).
__global__ __launch_bounds__(512) void attn_fwd(const bf16_t* __restrict__ Qp,
                                                const bf16_t* __restrict__ Kp,
                                                const bf16_t* __restrict__ Vt,
                                                bf16_t* __restrict__ Oattn) {
  const int bid = blockIdx.x;          // 0..511
  const int h   = bid & 15;            // (bid+256)&15 == h: CU pair same head
  const int idx = bid >> 4;            // 0..31
  const int qi  = idx < 16 ? 31 - idx : idx - 16;  // pair (31-i, i) per CU
  const int tid = threadIdx.x, lane = tid & 63, w = tid >> 6;
  const int g = lane >> 4, l15 = lane & 15;
  const int qrow = qi * 128 + w * 16;  // wave w owns 16 q-rows

  __shared__ alignas(16) bf16_t Ks[2][64][64];   // 16 KB, swizzled
  __shared__ alignas(16) bf16_t Vs[3][64][64];   // 24 KB, swizzled
  __shared__ alignas(16) bf16_t Plds[8][16][72]; // 18 KB, [q][k], 144B stride

  bf16x8 qf[2];
  {
    const bf16_t* qp = &Qp[(size_t)(qrow + l15) * E_DIM + h * 64 + g * 8];
    qf[0] = *(const bf16x8*)qp;
    qf[1] = *(const bf16x8*)(qp + 32);
  }

  bf16x8 ones;
#pragma unroll
  for (int i = 0; i < 8; ++i) ones[i] = (bf16_t)1.0f;

  // staging: 512 threads x 16B = one 64x64 bf16 tile per (K,V) issue
  const int row0 = tid >> 3, c0 = tid & 7;
  const int cgo = (c0 ^ (row0 & 7)) * 8;           // source-side swizzle
  const bf16_t* srcK = Kp + (size_t)row0 * E_DIM + h * 64 + cgo;
  const bf16_t* srcV = Vt + (size_t)(h * 64 + row0) * T_DIM + cgo;
  bf16_t* KsAll = &Ks[0][0][0];
  bf16_t* VsAll = &Vs[0][0][0];
  const size_t KADV = (size_t)64 * E_DIM;
  const int nt = 2 * qi + 2;

  auto issue = [&](int t) {
    gld_lds16(srcK + (size_t)t * KADV, KsAll + (t & 1) * 4096 + tid * 8);
    gld_lds16(srcV + (size_t)t * 64,   VsAll + (t % 3) * 4096 + tid * 8);
  };

  f32x4 acc[4] = {};          // acc[c][r]: O^T[d = c*16 + g*4 + r][q = l15]
  f32x4 acc_l = {};           // ones-trick row sums: acc_l[r] == l[q], all r
  float m_s = -1e30f;         // row-uniform running max

  auto pv = [&](int t) {
    const char* Vb = (const char*)(VsAll + (t % 3) * 4096);
    bf16x8 pf0 = *(const bf16x8*)&Plds[w][l15][g * 8];        // k = g*8..+7
    bf16x8 pf1 = *(const bf16x8*)&Plds[w][l15][32 + g * 8];   // k = 32+g*8..
#pragma unroll
    for (int c = 0; c < 4; ++c) {
      const int vr = c * 16 + l15;
      const char* rp = Vb + vr * 128;
      const int sw = (vr & 7) << 4;
      bf16x8 v0 = *(const bf16x8*)(rp + ((g * 16) ^ sw));
      bf16x8 v1 = *(const bf16x8*)(rp + ((64 + g * 16) ^ sw));
      acc[c] = __builtin_amdgcn_mfma_f32_16x16x32_bf16(v0, pf0, acc[c], 0, 0, 0);
      acc[c] = __builtin_amdgcn_mfma_f32_16x16x32_bf16(v1, pf1, acc[c], 0, 0, 0);
    }
    // l[q] += sum_k P[k][q] on the MFMA pipe (same pf fragments)
    acc_l = __builtin_amdgcn_mfma_f32_16x16x32_bf16(ones, pf0, acc_l, 0, 0, 0);
    acc_l = __builtin_amdgcn_mfma_f32_16x16x32_bf16(ones, pf1, acc_l, 0, 0, 0);
  };

  issue(0);

  for (int j = 0; j < nt; ++j) {
    asm volatile("s_waitcnt vmcnt(0)" ::: "memory");
    block_sync();                 // all waves' K_j,V_j resident; phase j-1 done
    if (j + 1 < nt) issue(j + 1);

    __builtin_amdgcn_s_setprio(1);
    if (j > 0) pv(j - 1);         // PV_{j-1}, one phase late (before rescale!)

    // S^T = K (Q*SCALE*log2e)^T from Ks[j&1]: s[j16][r] is
    // (k = j*64 + 16*j16 + 4*g + r, q = qrow + l15)
    const char* Kb = (const char*)(KsAll + (j & 1) * 4096);
    f32x4 s[4] = {};
#pragma unroll
    for (int j16 = 0; j16 < 4; ++j16) {
      const int r0 = j16 * 16 + l15;
      const char* rp = Kb + r0 * 128;
      const int sw = (r0 & 7) << 4;
      bf16x8 k0 = *(const bf16x8*)(rp + ((g * 16) ^ sw));
      bf16x8 k1 = *(const bf16x8*)(rp + ((64 + g * 16) ^ sw));
      s[j16] = __builtin_amdgcn_mfma_f32_16x16x32_bf16(k0, qf[0], s[j16], 0, 0, 0);
      s[j16] = __builtin_amdgcn_mfma_f32_16x16x32_bf16(k1, qf[1], s[j16], 0, 0, 0);
    }
    __builtin_amdgcn_s_setprio(0);

    // causal mask: k > q, on any tile overlapping/above this wave's rows
    const int kb = j * 64;
    if (kb + 63 > qrow) {
#pragma unroll
      for (int j16 = 0; j16 < 4; ++j16)
#pragma unroll
        for (int r = 0; r < 4; ++r)
          if (kb + j16 * 16 + g * 4 + r > qrow + l15) s[j16][r] = -1e30f;
    }

    // online softmax; pmax via nested max-triples (v_max3, 7 ops for 16)
    float t0 = fmaxf(fmaxf(s[0][0], s[0][1]), s[0][2]);
    float t1 = fmaxf(fmaxf(s[0][3], s[1][0]), s[1][1]);
    float t2 = fmaxf(fmaxf(s[1][2], s[1][3]), s[2][0]);
    float t3 = fmaxf(fmaxf(s[2][1], s[2][2]), s[2][3]);
    float t4 = fmaxf(fmaxf(s[3][0], s[3][1]), s[3][2]);
    float pmax = fmaxf(fmaxf(fmaxf(t0, t1), t2),
                       fmaxf(fmaxf(t3, t4), s[3][3]));

    if (!__all(pmax <= m_s + 11.0f)) {
      float rm = fmaxf(pmax, __shfl_xor(pmax, 16));
      rm = fmaxf(rm, __shfl_xor(rm, 32));     // row-uniform max
      float mn = fmaxf(m_s, rm);
      float sc = fexp2(m_s - mn);
      m_s = mn;
#pragma unroll
      for (int r = 0; r < 4; ++r) acc_l[r] *= sc;
#pragma unroll
      for (int c = 0; c < 4; ++c)
#pragma unroll
        for (int r = 0; r < 4; ++r) acc[c][r] *= sc;
    }

#pragma unroll
    for (int j16 = 0; j16 < 4; ++j16)
#pragma unroll
      for (int r = 0; r < 4; ++r)
        s[j16][r] = fexp2(s[j16][r] - m_s);

    // P -> LDS [q][k]: per j16 the 4 r-values are k-consecutive -> b64
#pragma unroll
    for (int j16 = 0; j16 < 4; ++j16) {
      bf16x4 pk;
      pk[0] = (bf16_t)s[j16][0]; pk[1] = (bf16_t)s[j16][1];
      pk[2] = (bf16_t)s[j16][2]; pk[3] = (bf16_t)s[j16][3];
      *(bf16x4*)&Plds[w][l15][j16 * 16 + g * 4] = pk;
    }
  }

  // epilogue: PV for the last tile; l comes straight from acc_l (no shfl)
  pv(nt - 1);

  const float inv = 1.0f / acc_l[0];
#pragma unroll
  for (int c = 0; c < 4; ++c) {
    bf16x4 o;
#pragma unroll
    for (int r = 0; r < 4; ++r) o[r] = (bf16_t)(acc[c][r] * inv);
    *(bf16x4*)&Oattn[(size_t)(qrow + l15) * E_DIM + h * 64 + c * 16 + g * 4] = o;
  }
}

extern "C" void kernel_launch(void* const* d_in, const int* in_sizes, int n_in,
                              void* d_out, int out_size, void* d_ws, size_t ws_size,
                              hipStream_t stream) {
  const float* q  = (const float*)d_in[0];
  const float* k  = (const float*)d_in[1];
  const float* v  = (const float*)d_in[2];
  const float* Wq = (const float*)d_in[3];
  const float* Wk = (const float*)d_in[4];
  const float* Wv = (const float*)d_in[5];
  const float* Wo = (const float*)d_in[6];
  float* out = (float*)d_out;

  const size_t TE = (size_t)T_DIM * E_DIM;   // 4M elems
  const size_t EE = (size_t)E_DIM * E_DIM;   // 1M elems
  dim3 blk(256);

  if (ws_size >= (size_t)56 * 1024 * 1024) {
    bf16_t* qb  = (bf16_t*)d_ws;          // reused as Oa after projections
    bf16_t* kb  = qb + TE;
    bf16_t* vb  = kb + TE;
    bf16_t* Wqb = vb + TE;
    bf16_t* Wkb = Wqb + EE;
    bf16_t* Wvb = Wkb + EE;
    bf16_t* Wob = Wvb + EE;
    bf16_t* Qp  = Wob + EE;
    bf16_t* Kp  = Qp + TE;
    bf16_t* Vt  = Kp + TE;                // [E][T]
    bf16_t* Oa  = qb;                     // alias

    cvt_all<<<2048, blk, 0, stream>>>(q, k, v, Wq, Wk, Wv, Wo,
                                      qb, kb, vb, Wqb, Wkb, Wvb, Wob);
    proj_qkv<<<dim3(768), blk, 0, stream>>>(qb, kb, vb, Wqb, Wkb, Wvb, Qp, Kp, Vt);
    attn_fwd<<<dim3(512), dim3(512), 0, stream>>>(Qp, Kp, Vt, Oa);
    gemm_fin<<<dim3(8, 64), blk, 0, stream>>>(Oa, Wob, out);
  } else {
    bf16_t* Qp = (bf16_t*)d_ws;
    bf16_t* Kp = Qp + TE;
    bf16_t* Vt = Kp + TE;
    bf16_t* Oa = Vt + TE;
    gemm_bt<float, float, bf16_t><<<dim3(8, 32), blk, 0, stream>>>(q, Wq, Qp, T_DIM, E_DIM, E_DIM, QSCALE_F);
    gemm_bt<float, float, bf16_t><<<dim3(8, 32), blk, 0, stream>>>(k, Wk, Kp, T_DIM, E_DIM, E_DIM, 1.0f);
    gemm_bt<float, float, bf16_t><<<dim3(32, 8), blk, 0, stream>>>(Wv, v, Vt, E_DIM, T_DIM, E_DIM, 1.0f);
    attn_fwd<<<dim3(512), dim3(512), 0, stream>>>(Qp, Kp, Vt, Oa);
    gemm_bt<bf16_t, float, float><<<dim3(8, 32), blk, 0, stream>>>(Oa, Wo, out, T_DIM, E_DIM, E_DIM, 1.0f);
  }
}